// Round 6
// baseline (357.258 us; speedup 1.0000x reference)
//
#include <hip/hip_runtime.h>

typedef __attribute__((ext_vector_type(8))) short short8;
typedef __attribute__((ext_vector_type(4))) short short4_;
typedef __attribute__((ext_vector_type(4))) float f32x4;

#define MFMA16(a, b, c) __builtin_amdgcn_mfma_f32_16x16x32_bf16(a, b, c, 0, 0, 0)

__device__ __forceinline__ short f2bf(float f) {
  unsigned u = __float_as_uint(f);
  unsigned r = (u + 0x7FFFu + ((u >> 16) & 1u)) >> 16;  // RNE
  return (short)r;
}

__device__ __forceinline__ void glds16(const short* g, short* l) {
  __builtin_amdgcn_global_load_lds((const __attribute__((address_space(1))) unsigned int*)g,
                                   (__attribute__((address_space(3))) unsigned int*)l, 16, 0, 0);
}

// f32 score swizzle: rotate within 32-word blocks by 4*(m&7)
__device__ __forceinline__ int sidx(int m, int j) {
  return (m << 10) + (j & ~31) + ((j + ((m & 7) << 2)) & 31);
}
// bf16 P swizzle: rotate within 64-elem blocks by 8*(m&7)
__device__ __forceinline__ int bidx(int m, int j) {
  return (m << 10) + (j & ~63) + ((j + ((m & 7) << 3)) & 63);
}

// ---------------- fused converts (q,k,v,pos,5 weights in one launch) ----------------
__global__ void cvt_all(const float* __restrict__ q, const float* __restrict__ k,
                        const float* __restrict__ v, const float* __restrict__ pos,
                        const float* __restrict__ W0, const float* __restrict__ W1,
                        const float* __restrict__ W2, const float* __restrict__ W3,
                        const float* __restrict__ W4, short* __restrict__ Xq,
                        short* __restrict__ Xk, short* __restrict__ Xv,
                        short* __restrict__ Xp, short* __restrict__ T0,
                        short* __restrict__ T1, short* __restrict__ T2,
                        short* __restrict__ T3, short* __restrict__ T4) {
  int id = blockIdx.x;
  int tid = threadIdx.x;
  if (id < 12288) {
    int which = id >> 12;
    int i = (id & 4095) * 256 + tid;
    const float* s = (which == 0) ? q : (which == 1) ? k : v;
    short* d = (which == 0) ? Xq : (which == 1) ? Xk : Xv;
    f32x4 x = ((const f32x4*)s)[i];
    short4_ o;
    o[0] = f2bf(x[0]); o[1] = f2bf(x[1]); o[2] = f2bf(x[2]); o[3] = f2bf(x[3]);
    ((short4_*)d)[i] = o;
  } else if (id < 20480) {
    int i = (id - 12288) * 256 + tid;
    int m = (i * 4) >> 9;
    short4_ o;
    if (m < 16376) {
      f32x4 x = ((const f32x4*)pos)[i];
      o[0] = f2bf(x[0]); o[1] = f2bf(x[1]); o[2] = f2bf(x[2]); o[3] = f2bf(x[3]);
    } else {
      o[0] = 0; o[1] = 0; o[2] = 0; o[3] = 0;
    }
    ((short4_*)Xp)[i] = o;
  } else {
    int t = id - 20480;
    int wsel = t >> 10;
    int i2 = (t & 1023) * 256 + tid;
    int n = i2 & 511, kk = i2 >> 9;
    const float* W = (wsel == 0) ? W0 : (wsel == 1) ? W1
                   : (wsel == 2) ? W2 : (wsel == 3) ? W3 : W4;
    short* T = (wsel == 0) ? T0 : (wsel == 1) ? T1
             : (wsel == 2) ? T2 : (wsel == 3) ? T3 : T4;
    T[n * 512 + kk] = f2bf(W[kk * 512 + n]);
  }
}

// ---------------- fused input projections (q,k,v,p) ----------------
// 128 rows x 256 cols per WG (2 n-tiles share one A staging). BK=32. 640 WGs.
__global__ __launch_bounds__(256, 2) void proj_in(
    const short* __restrict__ Xq, const short* __restrict__ Xk,
    const short* __restrict__ Xv, const short* __restrict__ Xp,
    const short* __restrict__ WtQ, const short* __restrict__ WtK,
    const short* __restrict__ WtV, const short* __restrict__ WtP,
    const float* __restrict__ biasU, const float* __restrict__ biasV,
    short* __restrict__ quB, short* __restrict__ qvB, short* __restrict__ kbB,
    short* __restrict__ vTB, short* __restrict__ pbB) {
  __shared__ short smem[12288];  // As [128][32]=4096, Bs [256][32]=8192
  short* As = smem;
  short* Bs = smem + 4096;

  const int tid = threadIdx.x;
  const int w = tid >> 6, l = tid & 63, q = l >> 4, c = l & 15;
  const int wm = (w & 1) << 6, wn = (w >> 1) << 6;

  int id = blockIdx.x;
  int mode, bx, by;
  const short *A, *Bt;
  if (id < 256) {
    mode = 3; bx = id & 127; by = id >> 7; A = Xp; Bt = WtP;
  } else if (id < 384) {
    mode = 0; id -= 256; bx = id & 63; by = id >> 6; A = Xq; Bt = WtQ;
  } else if (id < 512) {
    mode = 1; id -= 384; bx = id & 63; by = id >> 6; A = Xk; Bt = WtK;
  } else {
    mode = 2; id -= 512; bx = id & 63; by = id >> 6; A = Xv; Bt = WtV;
  }
  const int m0 = bx * 128, nbase = by * 256;

  f32x4 acc[2][4][4] = {};

  for (int kk = 0; kk < 512; kk += 32) {
#pragma unroll
    for (int i = 0; i < 2; i++) {
      int ci = i * 256 + tid;
      glds16(A + (m0 + (ci >> 2)) * 512 + kk + ((ci & 3) << 3), As + ci * 8);
    }
#pragma unroll
    for (int i = 0; i < 4; i++) {
      int ci = i * 256 + tid;
      glds16(Bt + (nbase + (ci >> 2)) * 512 + kk + ((ci & 3) << 3), Bs + ci * 8);
    }
    __syncthreads();
    short8 af[4], bf[2][4];
#pragma unroll
    for (int i = 0; i < 4; i++)
      af[i] = *(const short8*)(As + (wm + i * 16 + c) * 32 + q * 8);
#pragma unroll
    for (int n2 = 0; n2 < 2; n2++)
#pragma unroll
      for (int j = 0; j < 4; j++)
        bf[n2][j] = *(const short8*)(Bs + (n2 * 128 + wn + j * 16 + c) * 32 + q * 8);
#pragma unroll
    for (int n2 = 0; n2 < 2; n2++)
#pragma unroll
      for (int i = 0; i < 4; i++)
#pragma unroll
        for (int j = 0; j < 4; j++) acc[n2][i][j] = MFMA16(af[i], bf[n2][j], acc[n2][i][j]);
    __syncthreads();
  }

  if (mode == 2) {
    const int bq = m0 >> 10;
#pragma unroll
    for (int n2 = 0; n2 < 2; n2++) {
      int n0 = nbase + n2 * 128;
#pragma unroll
      for (int ch = 0; ch < 2; ch++) {
        __syncthreads();
        if ((w & 1) == ch) {
#pragma unroll
          for (int i = 0; i < 4; i++)
#pragma unroll
            for (int j = 0; j < 4; j++)
#pragma unroll
              for (int r = 0; r < 4; r++)
                smem[(i * 16 + q * 4 + r) * 128 + wn + j * 16 + c] = f2bf(acc[n2][i][j][r]);
        }
        __syncthreads();
        int d = tid >> 1, s0 = (tid & 1) << 5;
        int n = n0 + d, hh = n >> 6, dd = n & 63;
        int sbase = (m0 & 1023) + ch * 64 + s0;
        short* op = vTB + (((bq * 8 + hh) * 64 + dd) << 10) + sbase;
#pragma unroll
        for (int k2 = 0; k2 < 4; k2++) {
          short8 pk;
#pragma unroll
          for (int e = 0; e < 8; e++) pk[e] = smem[(s0 + k2 * 8 + e) * 128 + d];
          *(short8*)(op + (k2 << 3)) = pk;
        }
      }
    }
    return;
  }

#pragma unroll
  for (int n2 = 0; n2 < 2; n2++) {
    int n0 = nbase + n2 * 128;
#pragma unroll
    for (int i = 0; i < 4; i++)
#pragma unroll
      for (int j = 0; j < 4; j++) {
        int n = n0 + wn + j * 16 + c;
        float bu = 0.f, bv = 0.f;
        if (mode == 0) { bu = biasU[n]; bv = biasV[n]; }
#pragma unroll
        for (int r = 0; r < 4; r++) {
          int mg = m0 + wm + i * 16 + q * 4 + r;
          float v = acc[n2][i][j][r];
          if (mode == 0) {
            int b = mg >> 10, s = mg & 1023, h = n >> 6, d = n & 63;
            int idx = (((b * 8 + h) * 1024 + s) << 6) + d;
            quB[idx] = f2bf((v + bu) * 0.125f);
            qvB[idx] = f2bf((v + bv) * 0.125f);
          } else if (mode == 1) {
            int b = mg >> 10, s = mg & 1023, h = n >> 6, d = n & 63;
            kbB[(((b * 8 + h) * 1024 + s) << 6) + d] = f2bf(v);
          } else {
            if (mg < 16376) {
              int b = mg / 2047, rr = mg - b * 2047;
              int h = n >> 6, d = n & 63;
              pbB[(((b * 8 + h) * 2048 + rr) << 6) + d] = f2bf(v);
            }
          }
        }
      }
  }
}

// ---------------- output projection: 64x128 tile ----------------
__global__ __launch_bounds__(256, 3) void proj_out(
    const short* __restrict__ A, const short* __restrict__ Bt, float* __restrict__ C) {
  __shared__ short smem[2048 + 4096];
  short* As = smem;
  short* Bs = smem + 2048;

  const int tid = threadIdx.x;
  const int w = tid >> 6, l = tid & 63, q = l >> 4, c = l & 15;
  const int m0 = blockIdx.x * 64, n0 = blockIdx.y * 128;

  f32x4 acc[4][2] = {};

  for (int kk = 0; kk < 512; kk += 32) {
#pragma unroll
    for (int i = 0; i < 2; i++) {
      int ci = i * 256 + tid;
      glds16(Bt + (n0 + (ci >> 2)) * 512 + kk + ((ci & 3) << 3), Bs + ci * 8);
    }
    glds16(A + (m0 + (tid >> 2)) * 512 + kk + ((tid & 3) << 3), As + tid * 8);
    __syncthreads();
    short8 af[4], bf[2];
#pragma unroll
    for (int i = 0; i < 4; i++) af[i] = *(const short8*)(As + (i * 16 + c) * 32 + q * 8);
#pragma unroll
    for (int j = 0; j < 2; j++)
      bf[j] = *(const short8*)(Bs + (w * 32 + j * 16 + c) * 32 + q * 8);
#pragma unroll
    for (int i = 0; i < 4; i++)
#pragma unroll
      for (int j = 0; j < 2; j++) acc[i][j] = MFMA16(af[i], bf[j], acc[i][j]);
    __syncthreads();
  }

#pragma unroll
  for (int i = 0; i < 4; i++)
#pragma unroll
    for (int j = 0; j < 2; j++) {
      int n = n0 + w * 32 + j * 16 + c;
#pragma unroll
      for (int r = 0; r < 4; r++) {
        int mg = m0 + i * 16 + q * 4 + r;
        C[mg * 512 + n] = acc[i][j][r];
      }
    }
}

// ---------------- fused attention ----------------
// 1024 threads (16 waves), one WG per (b,h,32 q-rows). 128KB LDS -> 1 WG/CU.
// Pos band STORES every (m,j) exactly once (j=16rt+c+m-31 is a bijection), so
// content scores accumulate in registers concurrently, then RMW-add after one barrier.
__global__ __launch_bounds__(1024, 4) void attn_kernel(
    const short* __restrict__ qu, const short* __restrict__ qv,
    const short* __restrict__ kb, const short* __restrict__ vT,
    const short* __restrict__ pb, short* __restrict__ ctx) {
  __shared__ float sc[32 * 1024];
  __shared__ __align__(16) float rsArr[32];
  short* scb = (short*)sc;
  float* comb = sc + 16384;

  const int tid = threadIdx.x;
  const int w = tid >> 6, l = tid & 63, q = l >> 4, c = l & 15;
  const int bh = blockIdx.x & 63;
  const int i0 = (blockIdx.x >> 6) << 5;
  const int b = bh >> 3, h = bh & 7;

  f32x4 ccA[4][2];

  // Phase 1+2 interleaved: pos band (stores) + content (register accumulate)
  {
    const short* qpu = qu + (((bh << 10) + i0 + c) << 6) + q * 8;
    short8 u00 = *(const short8*)(qpu);
    short8 u01 = *(const short8*)(qpu + 32);
    short8 u10 = *(const short8*)(qpu + 16 * 64);
    short8 u11 = *(const short8*)(qpu + 16 * 64 + 32);
    const short* qpv = qv + (((bh << 10) + i0 + c) << 6) + q * 8;
    short8 v00 = *(const short8*)(qpv);
    short8 v01 = *(const short8*)(qpv + 32);
    short8 v10 = *(const short8*)(qpv + 16 * 64);
    short8 v11 = *(const short8*)(qpv + 16 * 64 + 32);
    const short* kpb = kb + (((bh << 10) + c) << 6) + q * 8;
    const short* ppb = pb + (((bh << 11) + c) << 6) + q * 8;
    const int r_lo = 992 - i0;
#pragma unroll
    for (int t = 0; t < 5; t++) {
      int rt = w + (t << 4);
      if (rt < 66) {
        int r0 = r_lo + (rt << 4);
        const short* pp = ppb + (r0 << 6);
        short8 b0 = *(const short8*)(pp);
        short8 b1 = *(const short8*)(pp + 32);
        f32x4 cc0 = {0.f, 0.f, 0.f, 0.f}, cc1 = {0.f, 0.f, 0.f, 0.f};
        cc0 = MFMA16(v00, b0, cc0);
        cc0 = MFMA16(v01, b1, cc0);
        cc1 = MFMA16(v10, b0, cc1);
        cc1 = MFMA16(v11, b1, cc1);
#pragma unroll
        for (int r = 0; r < 4; r++) {
          int m = q * 4 + r;
          int j = (rt << 4) + c + m - 31;
          if ((unsigned)j < 1024u) sc[sidx(m, j)] = cc0[r];
          int j1 = j + 16;
          if ((unsigned)j1 < 1024u) sc[sidx(m + 16, j1)] = cc1[r];
        }
      }
      if (t < 4) {
        int j0 = ((t << 4) + w) << 4;
        const short* kp = kpb + (j0 << 6);
        short8 b0 = *(const short8*)(kp);
        short8 b1 = *(const short8*)(kp + 32);
        f32x4 cc0 = {0.f, 0.f, 0.f, 0.f}, cc1 = {0.f, 0.f, 0.f, 0.f};
        cc0 = MFMA16(u00, b0, cc0);
        cc0 = MFMA16(u01, b1, cc0);
        cc1 = MFMA16(u10, b0, cc1);
        cc1 = MFMA16(u11, b1, cc1);
        ccA[t][0] = cc0;
        ccA[t][1] = cc1;
      }
    }
  }
  __syncthreads();
  // content RMW-add
#pragma unroll
  for (int t = 0; t < 4; t++) {
    int j0 = ((t << 4) + w) << 4;
#pragma unroll
    for (int r = 0; r < 4; r++) {
      int m = q * 4 + r;
      sc[sidx(m, j0 + c)] += ccA[t][0][r];
      sc[sidx(m + 16, j0 + c)] += ccA[t][1][r];
    }
  }
  __syncthreads();

  // V prefetch (independent of LDS) — hides L2 latency under softmax
  const int qt = w >> 2, wc = w & 3;
  const short* vp = vT + (((bh << 6) + wc * 16 + c) << 10) + (qt << 8) + q * 8;
  short8 pv0 = *(const short8*)(vp);
  short8 pv1 = *(const short8*)(vp + 32);
  short8 pv2 = *(const short8*)(vp + 64);
  short8 pv3 = *(const short8*)(vp + 96);

  // Phase 3: softmax; exp in registers, P written back as bf16 overlay
  {
    const int row = tid >> 5, c0 = tid & 31;
    const int rot = (row & 7) << 2;
    float* rb = sc + (row << 10);
    f32x4 v[8];
    float mx = -1e30f;
#pragma unroll
    for (int t = 0; t < 8; t++) {
      int j0 = (c0 + (t << 5)) << 2;
      v[t] = *(const f32x4*)(rb + (j0 & ~31) + ((j0 + rot) & 31));
      mx = fmaxf(fmaxf(fmaxf(v[t][0], v[t][1]), fmaxf(v[t][2], v[t][3])), mx);
    }
    mx = fmaxf(mx, __shfl_xor(mx, 1));
    mx = fmaxf(mx, __shfl_xor(mx, 2));
    mx = fmaxf(mx, __shfl_xor(mx, 4));
    mx = fmaxf(mx, __shfl_xor(mx, 8));
    mx = fmaxf(mx, __shfl_xor(mx, 16));
    __syncthreads();
    float sum = 0.f;
#pragma unroll
    for (int t = 0; t < 8; t++) {
      int j0 = (c0 << 2) + (t << 7);
      f32x4 e;
      e[0] = __expf(v[t][0] - mx); e[1] = __expf(v[t][1] - mx);
      e[2] = __expf(v[t][2] - mx); e[3] = __expf(v[t][3] - mx);
      sum += (e[0] + e[1]) + (e[2] + e[3]);
      short4_ o;
      o[0] = f2bf(e[0]); o[1] = f2bf(e[1]); o[2] = f2bf(e[2]); o[3] = f2bf(e[3]);
      *(short4_*)(scb + bidx(row, j0)) = o;
    }
    sum += __shfl_xor(sum, 1);
    sum += __shfl_xor(sum, 2);
    sum += __shfl_xor(sum, 4);
    sum += __shfl_xor(sum, 8);
    sum += __shfl_xor(sum, 16);
    if (c0 == 0) rsArr[row] = 1.0f / sum;
  }
  __syncthreads();

  // Phase 4: PV. wave = (qt, wc): key quarter qt, col-tile wc; both row-tiles.
  {
    f32x4 acc0 = {0.f, 0.f, 0.f, 0.f}, acc1 = {0.f, 0.f, 0.f, 0.f};
    const int rot8 = (c & 7) << 3;
    const short* prow0 = scb + (c << 10) + (qt << 8);
    const short* prow1 = prow0 + (16 << 10);
#pragma unroll
    for (int jt = 0; jt < 8; jt++) {
      int jj = jt << 5;
      short8 bv;
      if (jt == 0) bv = pv0;
      else if (jt == 1) bv = pv1;
      else if (jt == 2) bv = pv2;
      else if (jt == 3) bv = pv3;
      else bv = *(const short8*)(vp + jj);
      int off = (jj & ~63) + ((jj + q * 8 + rot8) & 63);
      short8 pa0 = *(const short8*)(prow0 + off);
      short8 pa1 = *(const short8*)(prow1 + off);
      acc0 = MFMA16(pa0, bv, acc0);
      acc1 = MFMA16(pa1, bv, acc1);
    }
    if (qt > 0) {
      float* cb = comb + (((qt - 1) * 8 + wc) << 8) + (l << 2);
      *(f32x4*)cb = acc0;
      *(f32x4*)(cb + (4 << 8)) = acc1;
    }
    __syncthreads();
    if (qt == 0) {
#pragma unroll
      for (int p3 = 0; p3 < 3; p3++) {
        const float* cb = comb + ((p3 * 8 + wc) << 8) + (l << 2);
        f32x4 p0 = *(const f32x4*)cb;
        f32x4 p1 = *(const f32x4*)(cb + (4 << 8));
#pragma unroll
        for (int r = 0; r < 4; r++) { acc0[r] += p0[r]; acc1[r] += p1[r]; }
      }
#pragma unroll
      for (int r = 0; r < 4; r++) {
        int m = q * 4 + r;
        float o0 = acc0[r] * rsArr[m];
        float o1 = acc1[r] * rsArr[m + 16];
        ctx[((b * 1024 + i0 + m) << 9) + h * 64 + wc * 16 + c] = f2bf(o0);
        ctx[((b * 1024 + i0 + 16 + m) << 9) + h * 64 + wc * 16 + c] = f2bf(o1);
      }
    }
  }
}

// ---------------- launcher ----------------

extern "C" void kernel_launch(void* const* d_in, const int* in_sizes, int n_in,
                              void* d_out, int out_size, void* d_ws, size_t ws_size,
                              hipStream_t stream) {
  const float* query = (const float*)d_in[0];
  const float* key   = (const float*)d_in[1];
  const float* value = (const float*)d_in[2];
  const float* pos   = (const float*)d_in[3];
  const float* Wq    = (const float*)d_in[4];
  const float* Wk    = (const float*)d_in[5];
  const float* Wv    = (const float*)d_in[6];
  const float* Wp    = (const float*)d_in[7];
  const float* ub    = (const float*)d_in[8];
  const float* vb    = (const float*)d_in[9];
  const float* Wo    = (const float*)d_in[10];

  char* p = (char*)d_ws;
  auto alloc = [&](size_t bytes) {
    char* r = p;
    p += (bytes + 255) & ~(size_t)255;
    return r;
  };
  short* Xq  = (short*)alloc(8192 * 512 * 2);
  short* Xk  = (short*)alloc(8192 * 512 * 2);
  short* Xv  = (short*)alloc(8192 * 512 * 2);
  short* Xp  = (short*)alloc((size_t)16384 * 512 * 2);
  short* WtQ = (short*)alloc(512 * 512 * 2);
  short* WtK = (short*)alloc(512 * 512 * 2);
  short* WtV = (short*)alloc(512 * 512 * 2);
  short* WtP = (short*)alloc(512 * 512 * 2);
  short* WtO = (short*)alloc(512 * 512 * 2);
  short* quB = (short*)alloc((size_t)8 * 8 * 1024 * 64 * 2);
  short* qvB = (short*)alloc((size_t)8 * 8 * 1024 * 64 * 2);
  short* kbB = (short*)alloc((size_t)8 * 8 * 1024 * 64 * 2);
  short* vTB = (short*)alloc((size_t)8 * 8 * 1024 * 64 * 2);
  short* pbB = (short*)alloc((size_t)8 * 8 * 2048 * 64 * 2);
  short* ctxB = (short*)alloc((size_t)8 * 1024 * 512 * 2);

  cvt_all<<<25600, 256, 0, stream>>>(query, key, value, pos, Wq, Wk, Wv, Wp, Wo,
                                     Xq, Xk, Xv, Xp, WtQ, WtK, WtV, WtP, WtO);

  proj_in<<<640, 256, 0, stream>>>(Xq, Xk, Xv, Xp, WtQ, WtK, WtV, WtP, ub, vb,
                                   quB, qvB, kbB, vTB, pbB);

  attn_kernel<<<2048, 1024, 0, stream>>>(quB, qvB, kbB, vTB, pbB, ctxB);

  proj_out<<<dim3(128, 4), 256, 0, stream>>>(ctxB, WtO, (float*)d_out);
}